// Round 4
// baseline (50.062 us; speedup 1.0000x reference)
//
#include <hip/hip_runtime.h>
#include <hip/hip_bf16.h>

typedef __attribute__((ext_vector_type(8))) short short8;
typedef __attribute__((ext_vector_type(4))) float f32x4;

#define WPB 16
#define BLOCK 1024
#define TPW 2                         // sequential tokens per wave
#define W_PITCH 528                   // 256 bf16 + 16B pad
#define W_MAT (64 * W_PITCH)          // 33792
#define QK_PITCH 144                  // 64 bf16 + 16B pad
#define QK_TILE (16 * QK_PITCH)       // 2304
#define LDS_W (2 * W_MAT)             // 67584
#define SCR_PW (2 * QK_TILE)          // Q tile + K tile per wave = 4608
#define LDS_TOTAL (LDS_W + WPB * SCR_PW)  // 141312 -> one 16-wave block/CU

union S8U { short8 s; unsigned u[4]; };

__device__ __forceinline__ unsigned pk2(float a, float b) {
  __hip_bfloat162 h = __float22bfloat162_rn(make_float2(a, b));
  return *reinterpret_cast<unsigned*>(&h);
}
__device__ __forceinline__ unsigned short bf1(float a) {
  __hip_bfloat16 h = __float2bfloat16(a);
  return *reinterpret_cast<unsigned short*>(&h);
}

// Full-row projection: ALL 16 global_load_dwordx4 issued up front (16KB/wave
// in flight), then 8 K-steps of convert + 4 B-frag LDS reads + 4 MFMAs.
#define PROJF(XROW, WLDS, ACC) {                                              \
  float4 xb_[16];                                                             \
  _Pragma("unroll") for (int i = 0; i < 16; ++i)                              \
    xb_[i] = *(const float4*)((XROW) + (i >> 1) * 32 + (i & 1) * 4);          \
  _Pragma("unroll") for (int ks = 0; ks < 8; ++ks) {                          \
    S8U u_;                                                                   \
    u_.u[0] = pk2(xb_[2 * ks].x, xb_[2 * ks].y);                              \
    u_.u[1] = pk2(xb_[2 * ks].z, xb_[2 * ks].w);                              \
    u_.u[2] = pk2(xb_[2 * ks + 1].x, xb_[2 * ks + 1].y);                      \
    u_.u[3] = pk2(xb_[2 * ks + 1].z, xb_[2 * ks + 1].w);                      \
    short8 af_ = u_.s;                                                        \
    _Pragma("unroll") for (int n = 0; n < 4; ++n) {                           \
      short8 bf_ = *(const short8*)((WLDS) + (n * 16 + e) * W_PITCH + ks * 64 + g * 16); \
      ACC[n] = __builtin_amdgcn_mfma_f32_16x16x32_bf16(af_, bf_, ACC[n], 0, 0, 0); \
    }                                                                         \
  } }

// C-frag (row=g*4+r, col=n*16+e) -> row-major bf16 tile
#define WRITET(ACC, TB) {                                                     \
  unsigned short* tw_ = (unsigned short*)(TB);                                \
  _Pragma("unroll") for (int n = 0; n < 4; ++n)                               \
    _Pragma("unroll") for (int r = 0; r < 4; ++r)                             \
      tw_[(g * 4 + r) * 72 + n * 16 + e] = bf1(ACC[n][r]); }

__global__ __launch_bounds__(BLOCK) void attrouter_kernel(
    const float* __restrict__ ig, const float* __restrict__ qev,
    const float* __restrict__ kev, const float* __restrict__ Wq,
    const float* __restrict__ Wk, float* __restrict__ out, int ntok)
{
  extern __shared__ char smem[];
  const int tid  = threadIdx.x;
  const int lane = tid & 63;
  const int wv   = tid >> 6;
  const int e    = lane & 15;
  const int g    = lane >> 4;

  // ---- stage W^T (bf16) into LDS; fold 1/sqrt(64) into Wq (exact 2^-3) ----
  {
    #pragma unroll
    for (int i = 0; i < 2; ++i) {
      int tile = tid + i * BLOCK;            // 0..2047
      int m  = tile >> 10;
      int r  = tile & 1023;
      int d0 = (r >> 4) * 4;
      int a0 = (r & 15) * 4;
      const float* wsrc = m ? Wk : Wq;
      const float scl = m ? 1.0f : 0.125f;
      const float* src = wsrc + d0 * 64 + a0;
      float4 r0 = *(const float4*)(src);
      float4 r1 = *(const float4*)(src + 64);
      float4 r2 = *(const float4*)(src + 128);
      float4 r3 = *(const float4*)(src + 192);
      float c0[4] = {r0.x, r0.y, r0.z, r0.w};
      float c1[4] = {r1.x, r1.y, r1.z, r1.w};
      float c2[4] = {r2.x, r2.y, r2.z, r2.w};
      float c3[4] = {r3.x, r3.y, r3.z, r3.w};
      #pragma unroll
      for (int j = 0; j < 4; ++j) {
        uint2 v;
        v.x = pk2(scl * c0[j], scl * c1[j]);
        v.y = pk2(scl * c2[j], scl * c3[j]);
        *(uint2*)(smem + m * W_MAT + (a0 + j) * W_PITCH + d0 * 2) = v;
      }
    }
  }
  __syncthreads();

  char* qt = smem + LDS_W + wv * SCR_PW;
  char* kt = qt + QK_TILE;

  const int wbase = (blockIdx.x * WPB + wv) * TPW;

  #pragma unroll
  for (int t = 0; t < TPW; ++t) {
    const int tok = wbase + t;
    if (tok >= ntok) break;
    const float* qrow = qev + (size_t)tok * 4096 + e * 256 + g * 8;
    const float* krow = kev + (size_t)tok * 4096 + e * 256 + g * 8;

    // ---- Q projection (16 loads in flight), flush to LDS tile ----
    f32x4 aq[4] = {{0,0,0,0},{0,0,0,0},{0,0,0,0},{0,0,0,0}};
    PROJF(qrow, smem, aq);
    WRITET(aq, qt);

    // ---- K projection (Q-acc and x-buffer regs free again) ----
    f32x4 ak[4] = {{0,0,0,0},{0,0,0,0},{0,0,0,0},{0,0,0,0}};
    PROJF(krow, smem + W_MAT, ak);
    WRITET(ak, kt);

    // ---- sim^T = mfma(K, Q): lane(e,g) reg r = sim[q=e][k=g*4+r] ----
    short8 fq0 = *(const short8*)(qt + e * QK_PITCH + g * 16);
    short8 fq1 = *(const short8*)(qt + e * QK_PITCH + 64 + g * 16);
    short8 fk0 = *(const short8*)(kt + e * QK_PITCH + g * 16);
    short8 fk1 = *(const short8*)(kt + e * QK_PITCH + 64 + g * 16);
    f32x4 s = {0, 0, 0, 0};
    s = __builtin_amdgcn_mfma_f32_16x16x32_bf16(fk0, fq0, s, 0, 0, 0);
    s = __builtin_amdgcn_mfma_f32_16x16x32_bf16(fk1, fq1, s, 0, 0, 0);

    // ---- softmax over k (in-lane + xor16/32), gate, final 16-way softmax ----
    float4 igv = *(const float4*)(ig + (size_t)tok * 16 + g * 4);
    float p0 = __expf(s[0]), p1 = __expf(s[1]);
    float p2 = __expf(s[2]), p3 = __expf(s[3]);
    float sg = p0 * igv.x + p1 * igv.y + p2 * igv.z + p3 * igv.w;
    float se = (p0 + p1) + (p2 + p3);
    sg += __shfl_xor(sg, 16); se += __shfl_xor(se, 16);
    sg += __shfl_xor(sg, 32); se += __shfl_xor(se, 32);
    float ev = __expf(sg / se);
    float ss = ev;
    ss += __shfl_xor(ss, 1); ss += __shfl_xor(ss, 2);
    ss += __shfl_xor(ss, 4); ss += __shfl_xor(ss, 8);
    if (g == 0) out[(size_t)tok * 16 + e] = ev / ss;
  }
}

extern "C" void kernel_launch(void* const* d_in, const int* in_sizes, int n_in,
                              void* d_out, int out_size, void* d_ws, size_t ws_size,
                              hipStream_t stream) {
  const float* ig  = (const float*)d_in[0];
  const float* qev = (const float*)d_in[1];
  const float* kev = (const float*)d_in[2];
  const float* Wq  = (const float*)d_in[3];
  const float* Wk  = (const float*)d_in[4];
  float* out = (float*)d_out;
  int ntok = in_sizes[1] >> 12;    // B*S

  hipFuncSetAttribute((const void*)attrouter_kernel,
                      hipFuncAttributeMaxDynamicSharedMemorySize, LDS_TOTAL);

  int grid = (ntok + WPB * TPW - 1) / (WPB * TPW);   // 256 at ntok=8192
  attrouter_kernel<<<grid, BLOCK, LDS_TOTAL, stream>>>(ig, qev, kev, Wq, Wk, out, ntok);
}

// Round 5
// 49.603 us; speedup vs baseline: 1.0093x; 1.0093x over previous
//
#include <hip/hip_runtime.h>
#include <hip/hip_bf16.h>

typedef __attribute__((ext_vector_type(8))) short short8;
typedef __attribute__((ext_vector_type(4))) float f32x4;

#define BLOCK 1024
#define TPI 4                     // tokens per iteration
#define NIT 8                     // iterations per block
#define TPB (TPI * NIT)           // 32 tokens per block
#define W_PITCH 528               // 256 bf16 + 16B pad
#define W_MAT (64 * W_PITCH)      // 33792
#define LDS_W (2 * W_MAT)         // 67584
#define X_PITCH 528
#define X_BLK (16 * X_PITCH)      // 8448 per (token,tensor)
#define XB LDS_W
#define LDS_X (TPI * 2 * X_BLK)   // 67584
#define CB (XB + LDS_X)           // 135168
#define C_PAIR 4608               // Q tile + K tile per token (pitch 144B)
#define LDS_TOTAL (CB + TPI * C_PAIR)  // 153600 <= 160K

__device__ __forceinline__ unsigned pk2(float a, float b) {
  __hip_bfloat162 h = __float22bfloat162_rn(make_float2(a, b));
  return *reinterpret_cast<unsigned*>(&h);
}
__device__ __forceinline__ unsigned short bf1(float a) {
  __hip_bfloat16 h = __float2bfloat16(a);
  return *reinterpret_cast<unsigned short*>(&h);
}

__global__ __launch_bounds__(BLOCK) void attrouter_kernel(
    const float* __restrict__ ig, const float* __restrict__ qev,
    const float* __restrict__ kev, const float* __restrict__ Wq,
    const float* __restrict__ Wk, float* __restrict__ out, int ntok)
{
  extern __shared__ char smem[];
  const int tid  = threadIdx.x;
  const int lane = tid & 63;
  const int wv   = tid >> 6;
  const int e    = lane & 15;
  const int g    = lane >> 4;

  // ---- stage W^T (bf16) into LDS; fold 1/sqrt(64) into Wq (exact 2^-3) ----
  {
    #pragma unroll
    for (int i = 0; i < 2; ++i) {
      int tile = tid + i * BLOCK;            // 0..2047
      int m  = tile >> 10;
      int r  = tile & 1023;
      int d0 = (r >> 4) * 4;
      int a0 = (r & 15) * 4;
      const float* wsrc = m ? Wk : Wq;
      const float scl = m ? 1.0f : 0.125f;
      const float* src = wsrc + d0 * 64 + a0;
      float4 r0 = *(const float4*)(src);
      float4 r1 = *(const float4*)(src + 64);
      float4 r2 = *(const float4*)(src + 128);
      float4 r3 = *(const float4*)(src + 192);
      float c0[4] = {r0.x, r0.y, r0.z, r0.w};
      float c1[4] = {r1.x, r1.y, r1.z, r1.w};
      float c2[4] = {r2.x, r2.y, r2.z, r2.w};
      float c3[4] = {r3.x, r3.y, r3.z, r3.w};
      #pragma unroll
      for (int j = 0; j < 4; ++j) {
        uint2 v;
        v.x = pk2(scl * c0[j], scl * c1[j]);
        v.y = pk2(scl * c2[j], scl * c3[j]);
        *(uint2*)(smem + m * W_MAT + (a0 + j) * W_PITCH + d0 * 2) = v;
      }
    }
  }
  __syncthreads();

  // wave decode: t4 = token-in-iter, tns = 0(q)/1(k), hn = staging row-half / compute n-pair
  const int t4  = wv >> 2;
  const int tns = (wv >> 1) & 1;
  const int hn  = wv & 1;

  const float* xsrc = tns ? kev : qev;
  char* xdst = smem + XB + (t4 * 2 + tns) * X_BLK + hn * 8 * X_PITCH + lane * 8;
  const char* xcomp = smem + XB + (t4 * 2 + tns) * X_BLK;
  const char* wlds  = smem + tns * W_MAT;
  unsigned short* ctile = (unsigned short*)(smem + CB + t4 * C_PAIR + tns * 2304);
  const int n0 = hn * 2, n1 = n0 + 1;

  const int tb0 = blockIdx.x * TPB;
  float4 xb[8];

  // contiguous 1KB-per-instruction wave loads: lane l reads 16B at l*16
#define LOADIT(IT) {                                                          \
    int tok_ = tb0 + (IT) * TPI + t4; if (tok_ >= ntok) tok_ = ntok - 1;      \
    const float* p_ = xsrc + (size_t)tok_ * 4096 + hn * 2048 + lane * 4;      \
    _Pragma("unroll") for (int r = 0; r < 8; ++r)                             \
      xb[r] = *(const float4*)(p_ + r * 256); }

  // bf16 convert + conflict-free ds_write_b64 (lane-contiguous 512B rows)
#define STAGEW() {                                                            \
    _Pragma("unroll") for (int r = 0; r < 8; ++r) {                           \
      uint2 v_; v_.x = pk2(xb[r].x, xb[r].y); v_.y = pk2(xb[r].z, xb[r].w);   \
      *(uint2*)(xdst + r * X_PITCH) = v_; } }

  // prologue: stage iteration 0
  LOADIT(0);
  __builtin_amdgcn_sched_barrier(0);
  STAGEW();
  __syncthreads();

  for (int it = 0; it < NIT; ++it) {
    const bool pf = (it + 1 < NIT);
    if (pf) LOADIT(it + 1);
    __builtin_amdgcn_sched_barrier(0);   // pin prefetch issue before compute

    // ---- projection MFMAs: this wave's (token, tensor, n-pair) ----
    f32x4 a0 = {0,0,0,0}, a1 = {0,0,0,0};
    #pragma unroll
    for (int ks = 0; ks < 8; ++ks) {
      short8 af = *(const short8*)(xcomp + e * X_PITCH + ks * 64 + g * 16);
      short8 b0 = *(const short8*)(wlds + (n0 * 16 + e) * W_PITCH + ks * 64 + g * 16);
      short8 b1 = *(const short8*)(wlds + (n1 * 16 + e) * W_PITCH + ks * 64 + g * 16);
      a0 = __builtin_amdgcn_mfma_f32_16x16x32_bf16(af, b0, a0, 0, 0, 0);
      a1 = __builtin_amdgcn_mfma_f32_16x16x32_bf16(af, b1, a1, 0, 0, 0);
    }
    // C-frag (row=g*4+r, col=n*16+e) -> token's Q/K tile
    #pragma unroll
    for (int r = 0; r < 4; ++r) {
      ctile[(g * 4 + r) * 72 + n0 * 16 + e] = bf1(a0[r]);
      ctile[(g * 4 + r) * 72 + n1 * 16 + e] = bf1(a1[r]);
    }
    __syncthreads();   // B1: X reads done, C tiles visible

    if (pf) STAGEW();  // overwrite X with next iteration (loads drained here)

    // ---- sim + softmax + gate + out: waves 0..3, one token each ----
    if (wv < TPI) {
      const int tok = tb0 + it * TPI + wv;
      if (tok < ntok) {
        const char* qt = smem + CB + wv * C_PAIR;
        const char* kt = qt + 2304;
        short8 fq0 = *(const short8*)(qt + e * 144 + g * 16);
        short8 fq1 = *(const short8*)(qt + e * 144 + 64 + g * 16);
        short8 fk0 = *(const short8*)(kt + e * 144 + g * 16);
        short8 fk1 = *(const short8*)(kt + e * 144 + 64 + g * 16);
        f32x4 s = {0,0,0,0};
        s = __builtin_amdgcn_mfma_f32_16x16x32_bf16(fk0, fq0, s, 0, 0, 0);
        s = __builtin_amdgcn_mfma_f32_16x16x32_bf16(fk1, fq1, s, 0, 0, 0);
        float4 igv = *(const float4*)(ig + (size_t)tok * 16 + g * 4);
        float p0 = __expf(s[0]), p1 = __expf(s[1]);
        float p2 = __expf(s[2]), p3 = __expf(s[3]);
        float sg = p0 * igv.x + p1 * igv.y + p2 * igv.z + p3 * igv.w;
        float se = (p0 + p1) + (p2 + p3);
        sg += __shfl_xor(sg, 16); se += __shfl_xor(se, 16);
        sg += __shfl_xor(sg, 32); se += __shfl_xor(se, 32);
        float ev = __expf(sg / se);
        float ss = ev;
        ss += __shfl_xor(ss, 1); ss += __shfl_xor(ss, 2);
        ss += __shfl_xor(ss, 4); ss += __shfl_xor(ss, 8);
        if (g == 0) out[(size_t)tok * 16 + e] = ev / ss;
      }
    }
    __syncthreads();   // B2: X(it+1) visible, C tiles free
  }
}

extern "C" void kernel_launch(void* const* d_in, const int* in_sizes, int n_in,
                              void* d_out, int out_size, void* d_ws, size_t ws_size,
                              hipStream_t stream) {
  const float* ig  = (const float*)d_in[0];
  const float* qev = (const float*)d_in[1];
  const float* kev = (const float*)d_in[2];
  const float* Wq  = (const float*)d_in[3];
  const float* Wk  = (const float*)d_in[4];
  float* out = (float*)d_out;
  int ntok = in_sizes[1] >> 12;    // B*S

  hipFuncSetAttribute((const void*)attrouter_kernel,
                      hipFuncAttributeMaxDynamicSharedMemorySize, LDS_TOTAL);

  int grid = (ntok + TPB - 1) / TPB;   // 256 at ntok=8192 -> 1 block/CU
  attrouter_kernel<<<grid, BLOCK, LDS_TOTAL, stream>>>(ig, qev, kev, Wq, Wk, out, ntok);
}